// Round 8
// baseline (238.358 us; speedup 1.0000x reference)
//
#include <hip/hip_runtime.h>
#include <math.h>

#define NBINS 8
#define IMG 224
#define HC 28                 // cells per side
#define OUTPER (HC*HC*NBINS)  // 6272
#define BATCH 256
#define PL (IMG*IMG)          // floats per plane (50176)
#define NPAIR 14              // cell-row pairs per image

typedef float v4f __attribute__((ext_vector_type(4)));

// pair-swap within quads (lane 2j <-> 2j+1): quad_perm(1,0,3,2) = 0xB1.
__device__ __forceinline__ float dpp_swap1(float x) {
    return __int_as_float(__builtin_amdgcn_update_dpp(
        0, __float_as_int(x), 0xB1, 0xF, 0xF, false));
}

// ---- one cell-row's HOG from the 18-row gray window v[BASE..BASE+9] ----
// Identical math to R6 (absmax 1.22e-4 verified). Returns sumsq contribution.
template<int BASE>
__device__ __forceinline__ float cell_row(
    const float4 (&v)[18], int lane, bool live,
    float ew0, float ew1, float ew2, float ew3,
    float* __restrict__ outp)
{
    const float E0 = 0.0021874911f, E1 = 0.043936934f,
                E2 = 0.32465247f,   E3 = 0.88249690f;
    const float EROW[8] = { E0, E1, E2, E3, E3, E2, E1, E0 };

    float h[8];
    #pragma unroll
    for (int k = 0; k < 8; ++k) h[k] = 0.f;

    auto pix = [&](float gx, float gy, float w) {
        float mag = __builtin_amdgcn_sqrtf(gx * gx + gy * gy + 1e-6f);
        float ax = fabsf(gx), ay = fabsf(gy);
        // exact-octant bin == floor(mod(atan2(gy,gx),2pi)/(pi/4));
        // boundary semantics verified in prior rounds — do not touch
        int bin;
        if (gy > 0.f)       bin = (gx > 0.f)  ? ((gy < gx) ? 0 : 1)
                                : (gx == 0.f) ? 2 : ((ay > ax) ? 2 : 3);
        else if (gy == 0.f) bin = (gx < 0.f) ? 4 : 0;
        else                bin = (gx < 0.f)  ? ((ay < ax) ? 4 : 5)
                                : (gx == 0.f) ? 6 : ((ay > ax) ? 6 : 7);
        float wm = w * mag;
        #pragma unroll
        for (int k = 0; k < 8; ++k) h[k] += (bin == k) ? wm : 0.f;
    };

    #pragma unroll
    for (int sr = 0; sr < 8; ++sr) {
        float4 t = v[BASE + sr], m = v[BASE + sr + 1], bt = v[BASE + sr + 2];
        float4 s, d;                       // vertical smooth / diff
        s.x = t.x + 2.f * m.x + bt.x;  s.y = t.y + 2.f * m.y + bt.y;
        s.z = t.z + 2.f * m.z + bt.z;  s.w = t.w + 2.f * m.w + bt.w;
        d.x = bt.x - t.x;  d.y = bt.y - t.y;
        d.z = bt.z - t.z;  d.w = bt.w - t.w;

        // lane-boundary neighbors (only 4 DS ops per row)
        float sL = __shfl_up(s.w, 1, 64);   sL = (lane == 0) ? 0.f : sL;
        float dL = __shfl_up(d.w, 1, 64);   dL = (lane == 0) ? 0.f : dL;
        float sR = __shfl_down(s.x, 1, 64); // lane55 <- lane56 == 0 (col224 pad)
        float dR = __shfl_down(d.x, 1, 64);

        float gx0 = s.y - sL,  gx1 = s.z - s.x,
              gx2 = s.w - s.y, gx3 = sR  - s.z;
        float gy0 = dL  + 2.f * d.x + d.y, gy1 = d.x + 2.f * d.y + d.z,
              gy2 = d.y + 2.f * d.z + d.w, gy3 = d.z + 2.f * d.w + dR;

        float er = EROW[sr];
        pix(gx0, gy0, er * ew0);
        pix(gx1, gy1, er * ew1);
        pix(gx2, gy2, er * ew2);
        pix(gx3, gy3, er * ew3);
    }

    // cell = lanes (2j, 2j+1): pair-reduce via DPP (VALU, no DS pipe)
    #pragma unroll
    for (int k = 0; k < 8; ++k) h[k] += dpp_swap1(h[k]);

    float ssq = 0.f;
    if (live) {
        bool odd = (lane & 1);
        float4 st = odd ? make_float4(h[4], h[5], h[6], h[7])
                        : make_float4(h[0], h[1], h[2], h[3]);
        *(float4*)outp = st;
        ssq = st.x * st.x + st.y * st.y + st.z * st.z + st.w * st.w;
    }
    return ssq;
}

// ---------------- main kernel: ONE WAVE per (image, cell-row PAIR) --------
// R8 line-dedup: the per-CU outstanding-line cap (~150 lines @ ~900ns ->
// 2.7 TB/s; confirmed R5/R6 depth-invariance, R7 cached-load symmetry)
// makes time proportional to HBM lines requested. 10-row waves read
// 280 rows/image (1.25x); 18-row waves covering TWO adjacent cell-rows
// read 252 (1.125x) -> -10% lines. All-NT retained (R7: any allocation
// evicts dirty ws-poison -> ~8us of writebacks). 54 loads issued in two
// depth-pinned phases; early converts cap peak VGPR ~195 (no spill).
__global__ __launch_bounds__(128) void hog_main_kernel(
    const float* __restrict__ x, float* __restrict__ out,
    float* __restrict__ partial)
{
    const int tid  = threadIdx.x;
    const int wv   = tid >> 6;
    const int lane = tid & 63;
    const int b    = blockIdx.y;
    const int crp  = blockIdx.x * 2 + wv;   // cell-row pair 0..13
    const int cr0  = crp * 2;
    const int r0   = cr0 * 8;               // first output row of the pair
    const int li   = lane < 55 ? lane : 55; // dead lanes read safe addrs
    const int col4 = li * 4;

    const float* base = x + (size_t)b * 3 * PL + col4;
    const bool edge = (crp == 0) || (crp == NPAIR - 1);

    float4 v[18];

    auto run = [&](auto EDGEC) {
        constexpr bool EDGE = decltype(EDGEC)::value;
        int off[18];
        #pragma unroll
        for (int j = 0; j < 18; ++j) {
            int gr  = r0 - 1 + j;
            int grc = EDGE ? (gr < 0 ? 0 : (gr > IMG - 1 ? IMG - 1 : gr)) : gr;
            off[j] = grc * IMG;
        }
        auto cvt = [&](int j, v4f R, v4f G, v4f B) {
            float4 g;
            g.x = 0.2989f * R.x + 0.587f * G.x + 0.114f * B.x;
            g.y = 0.2989f * R.y + 0.587f * G.y + 0.114f * B.y;
            g.z = 0.2989f * R.z + 0.587f * G.z + 0.114f * B.z;
            g.w = 0.2989f * R.w + 0.587f * G.w + 0.114f * B.w;
            int gr = r0 - 1 + j;
            bool z = (lane >= 56) || (EDGE && (gr < 0 || gr > IMG - 1));
            if (z) { g.x = 0.f; g.y = 0.f; g.z = 0.f; g.w = 0.f; }
            v[j] = g;
        };

        // phase 1: rows 0..9 (cell-row A window), row-major RGB
        v4f RA[10], GA[10], BA[10];
        #pragma unroll
        for (int j = 0; j < 10; ++j) {
            const v4f* p = (const v4f*)(base + off[j]);
            RA[j] = __builtin_nontemporal_load(p);
            GA[j] = __builtin_nontemporal_load(p + PL / 4);
            BA[j] = __builtin_nontemporal_load(p + 2 * (PL / 4));
        }
        __builtin_amdgcn_sched_barrier(0);
        // early converts free 18 v4f before phase-2 issue (VGPR cap)
        #pragma unroll
        for (int j = 0; j < 6; ++j) cvt(j, RA[j], GA[j], BA[j]);
        __builtin_amdgcn_sched_barrier(0);
        // phase 2: rows 10..17 (cell-row B remainder)
        v4f RB[8], GB[8], BB[8];
        #pragma unroll
        for (int j = 0; j < 8; ++j) {
            const v4f* p = (const v4f*)(base + off[10 + j]);
            RB[j] = __builtin_nontemporal_load(p);
            GB[j] = __builtin_nontemporal_load(p + PL / 4);
            BB[j] = __builtin_nontemporal_load(p + 2 * (PL / 4));
        }
        __builtin_amdgcn_sched_barrier(0);
        #pragma unroll
        for (int j = 6; j < 10; ++j) cvt(j, RA[j], GA[j], BA[j]);
        #pragma unroll
        for (int j = 0; j < 8; ++j) cvt(10 + j, RB[j], GB[j], BB[j]);
    };
    if (edge) run(std::integral_constant<bool, true>{});
    else      run(std::integral_constant<bool, false>{});

    // separable gauss: w(sr, col) = EROW[sr] * ECOL[col&7]; ECOL symmetric
    const float E0 = 0.0021874911f, E1 = 0.043936934f,
                E2 = 0.32465247f,   E3 = 0.88249690f;
    const bool odd = (lane & 1);
    const float ew0 = odd ? E3 : E0, ew1 = odd ? E2 : E1,
                ew2 = odd ? E1 : E2, ew3 = odd ? E0 : E3;

    const bool live = (lane < 56);
    float* outA = out + (size_t)b * OUTPER + (size_t)cr0 * IMG + 4 * li;
    float ssq  = cell_row<0>(v, lane, live, ew0, ew1, ew2, ew3, outA);
    ssq       += cell_row<8>(v, lane, live, ew0, ew1, ew2, ew3, outA + IMG);

    // per-(image, pair) sumsq partial
    #pragma unroll
    for (int o = 32; o > 0; o >>= 1) ssq += __shfl_down(ssq, o, 64);
    if (lane == 0) partial[b * NPAIR + crp] = ssq;
}

// ---------------- norm kernel: FOUR blocks (256 thr) per image -------------
__global__ __launch_bounds__(256) void hog_norm_kernel(
    float* __restrict__ out, const float* __restrict__ partial)
{
    const int bq = blockIdx.x, tid = threadIdx.x;
    const int b = bq >> 2, q = bq & 3;
    __shared__ float wsum[4];
    __shared__ float s_inv;
    float s = (tid < NPAIR) ? partial[b * NPAIR + tid] : 0.f;  // lanes 0..13
    #pragma unroll
    for (int o = 32; o > 0; o >>= 1) s += __shfl_down(s, o, 64);
    if ((tid & 63) == 0) wsum[tid >> 6] = s;
    __syncthreads();
    if (tid == 0) {
        float t = wsum[0] + wsum[1] + wsum[2] + wsum[3];
        s_inv = 1.0f / (sqrtf(t) + 1e-6f);
    }
    __syncthreads();
    float inv = s_inv;
    float4* o4 = (float4*)(out + (size_t)b * OUTPER + (size_t)q * (OUTPER / 4));
    for (int i = tid; i < OUTPER / 16; i += 256) {   // 392 float4 per quarter
        float4 w = o4[i];
        w.x *= inv; w.y *= inv; w.z *= inv; w.w *= inv;
        o4[i] = w;
    }
}

extern "C" void kernel_launch(void* const* d_in, const int* in_sizes, int n_in,
                              void* d_out, int out_size, void* d_ws, size_t ws_size,
                              hipStream_t stream) {
    const float* x = (const float*)d_in[0];
    // d_in[1]=gauss (separable constants inlined), d_in[2]=kx, d_in[3]=ky
    float* out     = (float*)d_out;
    float* partial = (float*)d_ws;       // 3584 floats, fully overwritten

    hog_main_kernel<<<dim3(7, BATCH), 128, 0, stream>>>(x, out, partial);
    hog_norm_kernel<<<BATCH * 4, 256, 0, stream>>>(out, partial);
}

// Round 9
// 223.376 us; speedup vs baseline: 1.0671x; 1.0671x over previous
//
#include <hip/hip_runtime.h>
#include <math.h>

#define NBINS 8
#define IMG 224
#define HC 28                 // cells per side
#define OUTPER (HC*HC*NBINS)  // 6272
#define BATCH 256
#define PL (IMG*IMG)          // floats per plane (50176)

typedef float v4f __attribute__((ext_vector_type(4)));

// pair-swap within quads (lane 2j <-> 2j+1): quad_perm(1,0,3,2) = 0xB1.
__device__ __forceinline__ float dpp_swap1(float x) {
    return __int_as_float(__builtin_amdgcn_update_dpp(
        0, __float_as_int(x), 0xB1, 0xF, 0xF, false));
}

// ---- gray loader: lane owns cols 4i..4i+3 of rows r0-1..r0+8 ----
// DEPTH-MAX: all 30 nt loads (10 rows x RGB) are issued back-to-back into
// 30 dedicated float4 regs BEFORE any FMA (sched_barrier pins the boundary).
// NT loads: any cache-allocating read evicts the 602MB dirty ws-poison from
// L2/L3 -> concurrent HBM writebacks (R5: nt beats cached by ~5us; R7:
// partial cached regressed ~8us). Read wall measured at ~2.7 TB/s across
// six access structures (R0-R8) -> per-CU outstanding-line service cap;
// this structure sits ~4% above that floor. R8 (pair-waves, -10% lines)
// regressed +15us on structure cost -> this is the measured optimum.
template<bool EDGE>
__device__ __forceinline__ void load_gray(const float* __restrict__ xb,
                                          int r0, int col4, int lane,
                                          float4 v[10])
{
    const float* base = xb + col4;
    int off[10];
    #pragma unroll
    for (int j = 0; j < 10; ++j) {
        int gr  = r0 - 1 + j;
        int grc = EDGE ? (gr < 0 ? 0 : (gr > IMG - 1 ? IMG - 1 : gr)) : gr;
        off[j] = grc * IMG;
    }
    v4f R[10], G[10], B[10];
    #pragma unroll
    for (int j = 0; j < 10; ++j)
        R[j] = __builtin_nontemporal_load((const v4f*)(base + off[j]));
    #pragma unroll
    for (int j = 0; j < 10; ++j)
        G[j] = __builtin_nontemporal_load((const v4f*)(base + off[j] + PL));
    #pragma unroll
    for (int j = 0; j < 10; ++j)
        B[j] = __builtin_nontemporal_load((const v4f*)(base + off[j] + 2 * PL));
    __builtin_amdgcn_sched_barrier(0);   // keep all 30 issued before converts
    #pragma unroll
    for (int j = 0; j < 10; ++j) {
        int gr = r0 - 1 + j;
        float4 g;
        g.x = 0.2989f * R[j].x + 0.587f * G[j].x + 0.114f * B[j].x;
        g.y = 0.2989f * R[j].y + 0.587f * G[j].y + 0.114f * B[j].y;
        g.z = 0.2989f * R[j].z + 0.587f * G[j].z + 0.114f * B[j].z;
        g.w = 0.2989f * R[j].w + 0.587f * G[j].w + 0.114f * B[j].w;
        bool z = (lane >= 56) || (EDGE && (gr < 0 || gr > IMG - 1));
        if (z) { g.x = 0.f; g.y = 0.f; g.z = 0.f; g.w = 0.f; }
        v[j] = g;
    }
}

// ---------------- main kernel: ONE WAVE per (image, cell-row) -------------
// grid (7, BATCH): block = 4 waves = 4 consecutive cell-rows of one image.
// Lane i (0..55) owns output cols 4i..4i+3, separable Sobel in-register
// (4 shfl per row), register histogram, DPP pair-reduce, one coalesced
// float4 store per lane. Numerics identical to R2/R5/R6 (absmax 1.22e-4).
__global__ __launch_bounds__(256) void hog_main_kernel(
    const float* __restrict__ x, float* __restrict__ out,
    float* __restrict__ partial)
{
    const int tid  = threadIdx.x;
    const int wv   = tid >> 6;
    const int lane = tid & 63;
    const int b    = blockIdx.y;
    const int cr   = blockIdx.x * 4 + wv;   // cell row 0..27
    const int r0   = cr * 8;
    const int li   = lane < 55 ? lane : 55; // dead lanes read safe addrs
    const int col4 = li * 4;

    const float* xb = x + (size_t)b * 3 * PL;

    float4 v[10];
    if (cr == 0 || cr == HC - 1) load_gray<true >(xb, r0, col4, lane, v);
    else                         load_gray<false>(xb, r0, col4, lane, v);

    // separable gauss: w(sr, col) = EROW[sr] * ECOL[col&7]; ECOL symmetric
    const float E0 = 0.0021874911f, E1 = 0.043936934f,
                E2 = 0.32465247f,   E3 = 0.88249690f;
    const bool odd = (lane & 1);
    const float ew0 = odd ? E3 : E0, ew1 = odd ? E2 : E1,
                ew2 = odd ? E1 : E2, ew3 = odd ? E0 : E3;
    const float EROW[8] = { E0, E1, E2, E3, E3, E2, E1, E0 };

    float h[8];
    #pragma unroll
    for (int k = 0; k < 8; ++k) h[k] = 0.f;

    auto pix = [&](float gx, float gy, float w) {
        float mag = __builtin_amdgcn_sqrtf(gx * gx + gy * gy + 1e-6f);
        float ax = fabsf(gx), ay = fabsf(gy);
        // exact-octant bin == floor(mod(atan2(gy,gx),2pi)/(pi/4));
        // boundary semantics verified in prior rounds — do not touch
        int bin;
        if (gy > 0.f)       bin = (gx > 0.f)  ? ((gy < gx) ? 0 : 1)
                                : (gx == 0.f) ? 2 : ((ay > ax) ? 2 : 3);
        else if (gy == 0.f) bin = (gx < 0.f) ? 4 : 0;
        else                bin = (gx < 0.f)  ? ((ay < ax) ? 4 : 5)
                                : (gx == 0.f) ? 6 : ((ay > ax) ? 6 : 7);
        float wm = w * mag;
        #pragma unroll
        for (int k = 0; k < 8; ++k) h[k] += (bin == k) ? wm : 0.f;
    };

    #pragma unroll
    for (int sr = 0; sr < 8; ++sr) {
        float4 t = v[sr], m = v[sr + 1], bt = v[sr + 2];
        float4 s, d;                       // vertical smooth / diff
        s.x = t.x + 2.f * m.x + bt.x;  s.y = t.y + 2.f * m.y + bt.y;
        s.z = t.z + 2.f * m.z + bt.z;  s.w = t.w + 2.f * m.w + bt.w;
        d.x = bt.x - t.x;  d.y = bt.y - t.y;
        d.z = bt.z - t.z;  d.w = bt.w - t.w;

        // lane-boundary neighbors (only 4 DS ops per row)
        float sL = __shfl_up(s.w, 1, 64);   sL = (lane == 0) ? 0.f : sL;
        float dL = __shfl_up(d.w, 1, 64);   dL = (lane == 0) ? 0.f : dL;
        float sR = __shfl_down(s.x, 1, 64); // lane55 <- lane56 == 0 (col224 pad)
        float dR = __shfl_down(d.x, 1, 64);

        float gx0 = s.y - sL,  gx1 = s.z - s.x,
              gx2 = s.w - s.y, gx3 = sR  - s.z;
        float gy0 = dL  + 2.f * d.x + d.y, gy1 = d.x + 2.f * d.y + d.z,
              gy2 = d.y + 2.f * d.z + d.w, gy3 = d.z + 2.f * d.w + dR;

        float er = EROW[sr];
        pix(gx0, gy0, er * ew0);
        pix(gx1, gy1, er * ew1);
        pix(gx2, gy2, er * ew2);
        pix(gx3, gy3, er * ew3);
    }

    // cell = lanes (2j, 2j+1): pair-reduce via DPP (VALU, no DS pipe)
    #pragma unroll
    for (int k = 0; k < 8; ++k) h[k] += dpp_swap1(h[k]);

    float ssq = 0.f;
    if (lane < 56) {
        float4 st = odd ? make_float4(h[4], h[5], h[6], h[7])
                        : make_float4(h[0], h[1], h[2], h[3]);
        *(float4*)(out + (size_t)b * OUTPER + (size_t)cr * IMG + 4 * lane) = st;
        ssq = st.x * st.x + st.y * st.y + st.z * st.z + st.w * st.w;
    }

    // per-(image, cell-row) sumsq partial
    #pragma unroll
    for (int o = 32; o > 0; o >>= 1) ssq += __shfl_down(ssq, o, 64);
    if (lane == 0) partial[b * HC + cr] = ssq;
}

// ---------------- norm kernel: FOUR blocks (256 thr) per image -------------
__global__ __launch_bounds__(256) void hog_norm_kernel(
    float* __restrict__ out, const float* __restrict__ partial)
{
    const int bq = blockIdx.x, tid = threadIdx.x;
    const int b = bq >> 2, q = bq & 3;
    __shared__ float wsum[4];
    __shared__ float s_inv;
    float s = (tid < HC) ? partial[b * HC + tid] : 0.f;   // lanes 0..27, wave 0
    #pragma unroll
    for (int o = 32; o > 0; o >>= 1) s += __shfl_down(s, o, 64);
    if ((tid & 63) == 0) wsum[tid >> 6] = s;
    __syncthreads();
    if (tid == 0) {
        float t = wsum[0] + wsum[1] + wsum[2] + wsum[3];
        s_inv = 1.0f / (sqrtf(t) + 1e-6f);
    }
    __syncthreads();
    float inv = s_inv;
    float4* o4 = (float4*)(out + (size_t)b * OUTPER + (size_t)q * (OUTPER / 4));
    for (int i = tid; i < OUTPER / 16; i += 256) {   // 392 float4 per quarter
        float4 w = o4[i];
        w.x *= inv; w.y *= inv; w.z *= inv; w.w *= inv;
        o4[i] = w;
    }
}

extern "C" void kernel_launch(void* const* d_in, const int* in_sizes, int n_in,
                              void* d_out, int out_size, void* d_ws, size_t ws_size,
                              hipStream_t stream) {
    const float* x = (const float*)d_in[0];
    // d_in[1]=gauss (separable constants inlined), d_in[2]=kx, d_in[3]=ky
    float* out     = (float*)d_out;
    float* partial = (float*)d_ws;       // 7168 floats, fully overwritten

    hog_main_kernel<<<dim3(7, BATCH), 256, 0, stream>>>(x, out, partial);
    hog_norm_kernel<<<BATCH * 4, 256, 0, stream>>>(out, partial);
}